// Round 8
// baseline (211.687 us; speedup 1.0000x reference)
//
#include <hip/hip_runtime.h>

// Problem: S=8192, K=1024, O=4096
// out_q[s,o] = clip(round(int8dot(x[s,:], w[o,:]) * sx*sw/sy[s]), -128, 127)
// d_out = [ out_q as float (S*O) | scale_y (S) ]
//
// R13 = exact R8 gemm chassis (best, 199.6 us) + two untouched-axis fixes:
//  (1) pack v2: 4 lanes per 16B output chunk. Old pack: lane reads 64B at
//      lane-stride 64 -> 64 cache-line requests per wave-load (4x the
//      minimum). New: coalesced dwordx4 loads (16 lines/wave-load, minimum)
//      + contiguous dword stores. Output image BYTE-IDENTICAL to verified.
//  (2) C-writes via __builtin_nontemporal_store: 134 MB of fp32 output no
//      longer thrashes the 4MB/XCD L2 that the staging path re-reads A/B
//      panels from 16-32x.
// History: R7 -20 (occupancy); R8 +1 best (counted-vmcnt null on 2-phase);
// R9 -12.7, R11 -9.4 (8-phase family loses at 1 blk/CU); R10 0 (XCD swz);
// R12 -6.3 (32x32 shape, bank-conflict in derived layout).

#define S_DIM 8192
#define K_DIM 1024
#define O_DIM 4096
#define BM 256
#define BN 128
#define BK 64
#define NITER (K_DIM / BK)
#define TILE_BYTES (128 * BK)   // 8192 B band-tile (pack layout unit)
#define A_SLOT (2 * TILE_BYTES) // 16 KB: two band-tiles stacked
#define B_SLOT TILE_BYTES       // 8 KB

using i32x4 = __attribute__((ext_vector_type(4))) int;

__device__ __forceinline__ void load_lds16(const void* g, void* l) {
  __builtin_amdgcn_global_load_lds(
      (const __attribute__((address_space(1))) void*)g,
      (__attribute__((address_space(3))) void*)l, 16, 0, 0);
}

// ---------------- pack v2: int32 -> int8, coalesced 4-lane scheme ------------
// Output image identical to the verified R5/R8 pack:
//   tile t = band*16 + ktile; within tile, byte r*64 + cs*16 holds chunk
//   (cs ^ (r&3)) of row band*128+r.
// Thread q -> chunk j = q>>2, dword sub = q&3. Load: one int4 (16 B) at
// int4-index row*256 + kt*16 + c*4 + sub  (lanes sub=0..3 cover the chunk's
// 64 B contiguously; a wave covers 4 rows x 256 B = 16 full 64B lines).
// Store: dword at t*2048 + idx*4 + sub  (wave writes 256 B contiguous).
__global__ void pack_kernel(const int* __restrict__ xi, const int* __restrict__ wi,
                            const float* __restrict__ sy,
                            unsigned* __restrict__ ap, unsigned* __restrict__ bp,
                            float* __restrict__ out_sy) {
  const int tid = blockIdx.x * blockDim.x + threadIdx.x;
  const int nA4 = S_DIM * K_DIM / 4;  // 2M output dwords for A
  const int nB4 = O_DIM * K_DIM / 4;  // 1M output dwords for B

  const int* src;
  unsigned* dst;
  int q;
  if (tid < nA4) {
    src = xi; dst = ap; q = tid;
  } else if (tid < nA4 + nB4) {
    src = wi; dst = bp; q = tid - nA4;
  } else {
    return;
  }
  const int j = q >> 2;          // chunk index
  const int sub = q & 3;         // dword within chunk
  const int t = j >> 9;          // tile index (512 chunks/tile)
  const int idx = j & 511;
  const int r = idx >> 2;        // row within tile 0..127
  const int cs = idx & 3;        // chunk slot
  const int c = cs ^ (r & 3);    // global chunk (swizzle)
  const int band = t >> 4;       // 16 ktiles per band
  const int kt = t & 15;
  const int row = band * 128 + r;
  const int4 v = *((const int4*)src + row * 256 + kt * 16 + c * 4 + sub);
  const unsigned o = (v.x & 0xff) | ((v.y & 0xff) << 8) | ((v.z & 0xff) << 16) |
                     (((unsigned)v.w & 0xff) << 24);
  dst[(size_t)t * 2048 + idx * 4 + sub] = o;
  if (tid < S_DIM) out_sy[tid] = sy[tid];
}

// ---------------- int8 MFMA GEMM, 256x128 tile, ring-3, 16 waves/CU ----------
// (exact R8 structure; only the C-store is now nontemporal)
// 512 threads = 8 waves in 4x2; wave owns 64x64 = 4x4 grid of 16x16x64 tiles.
// 3-slot LDS ring (72 KB, 2 blk/CU), 2-deep prefetch, counted waits:
//   s_waitcnt vmcnt(3) lgkmcnt(0) ; s_barrier ; issue stage(t+2) ; compute(t)
__global__ __launch_bounds__(512, 4) void gemm_i8_kernel(
    const signed char* __restrict__ Ap,  // tiled-packed x
    const signed char* __restrict__ Bp,  // tiled-packed w
    const float* __restrict__ sx, const float* __restrict__ sw,
    const float* __restrict__ sy, float* __restrict__ out) {
  __shared__ __align__(16) signed char As[3][A_SLOT];  // 48 KB
  __shared__ __align__(16) signed char Bs[3][B_SLOT];  // 24 KB

  const int tid = threadIdx.x;
  const int wave = tid >> 6;
  const int lane = tid & 63;
  const int wm = wave >> 1;  // 0..3: wave row in block
  const int wn = wave & 1;   // 0..1: wave col in block
  const int rowBase = blockIdx.x * BM;   // x-fast over S keeps B L2-resident
  const int colBase = blockIdx.y * BN;

  const int soff = wave * 1024 + lane * 16;  // 8 waves cover 8 KB per call
  const signed char* gA0 = Ap + (size_t)(2 * blockIdx.x) * NITER * TILE_BYTES + soff;
  const signed char* gA1 = Ap + (size_t)(2 * blockIdx.x + 1) * NITER * TILE_BYTES + soff;
  const signed char* gB  = Bp + (size_t)blockIdx.y * NITER * TILE_BYTES + soff;
  signed char* ldsA = (signed char*)As + soff;  // + slot*A_SLOT (+TILE for half1)
  signed char* ldsB = (signed char*)Bs + soff;  // + slot*B_SLOT

  i32x4 acc[4][4] = {};

  const int fr = lane & 15;                            // fragment row
  const int fq = (((lane >> 4) ^ (fr & 3)) & 3) * 16;  // swizzled chunk slot

  // Prologue: stage K-tiles 0 and 1 into ring slots 0 and 1 (ordered groups).
  load_lds16(gA0, ldsA);
  load_lds16(gA1, ldsA + TILE_BYTES);
  load_lds16(gB, ldsB);
  asm volatile("" ::: "memory");
  {
    const size_t goff = TILE_BYTES;
    load_lds16(gA0 + goff, ldsA + A_SLOT);
    load_lds16(gA1 + goff, ldsA + A_SLOT + TILE_BYTES);
    load_lds16(gB + goff, ldsB + B_SLOT);
  }

#pragma unroll
  for (int it = 0; it < NITER; ++it) {
    // Drain own stage(it) (oldest 3); keep stage(it+1)'s 3 in flight.
    // lgkmcnt(0): no live ds_read of slot(it-1) before its overwrite below.
    if (it + 1 < NITER) {
      asm volatile("s_waitcnt vmcnt(3) lgkmcnt(0)" ::: "memory");
    } else {
      asm volatile("s_waitcnt vmcnt(0) lgkmcnt(0)" ::: "memory");
    }
    __builtin_amdgcn_s_barrier();
    asm volatile("" ::: "memory");  // no memory op crosses the barrier

    if (it + 2 < NITER) {  // 2-deep prefetch into ring slot (it+2)%3
      const int slot = (it + 2) % 3;
      const size_t goff = (size_t)(it + 2) * TILE_BYTES;
      load_lds16(gA0 + goff, ldsA + slot * A_SLOT);
      load_lds16(gA1 + goff, ldsA + slot * A_SLOT + TILE_BYTES);
      load_lds16(gB + goff, ldsB + slot * B_SLOT);
    }

    const signed char* curA = As[it % 3];
    const signed char* curB = Bs[it % 3];
    i32x4 bf[4];
#pragma unroll
    for (int ni = 0; ni < 4; ++ni)
      bf[ni] = *(const i32x4*)(curB + (wn * 64 + ni * 16 + fr) * BK + fq);

#pragma unroll
    for (int mi = 0; mi < 4; ++mi) {
      i32x4 af = *(const i32x4*)(curA + (wm * 64 + mi * 16 + fr) * BK + fq);
#pragma unroll
      for (int ni = 0; ni < 4; ++ni)
        acc[mi][ni] =
            __builtin_amdgcn_mfma_i32_16x16x64_i8(af, bf[ni], acc[mi][ni], 0, 0, 0);
    }
  }

  // Epilogue. C/D layout: col = lane&15, row = (lane>>4)*4 + reg.
  // Nontemporal stores: 134 MB of C must not evict the L2-resident A/B
  // panels that staging re-reads 16-32x.
  const float sxw = sx[0] * sw[0];
  const int quad = lane >> 4;
#pragma unroll
  for (int mi = 0; mi < 4; ++mi) {
#pragma unroll
    for (int r = 0; r < 4; ++r) {
      const int s = rowBase + wm * 64 + mi * 16 + quad * 4 + r;
      const float rs = sxw / sy[s];
      float* orow = out + (size_t)s * O_DIM + colBase + wn * 64 + fr;
#pragma unroll
      for (int ni = 0; ni < 4; ++ni) {
        float f = rintf((float)acc[mi][ni][r] * rs);
        f = fminf(127.0f, fmaxf(-128.0f, f));
        __builtin_nontemporal_store(f, orow + ni * 16);
      }
    }
  }
}

extern "C" void kernel_launch(void* const* d_in, const int* in_sizes, int n_in,
                              void* d_out, int out_size, void* d_ws, size_t ws_size,
                              hipStream_t stream) {
  const int* x = (const int*)d_in[0];        // [S,K] int8 values as int32
  const int* w = (const int*)d_in[1];        // [O,K] int8 values as int32
  const float* sx = (const float*)d_in[2];
  const float* sw = (const float*)d_in[3];
  const float* sy = (const float*)d_in[4];   // [S]
  float* out = (float*)d_out;

  unsigned* ap = (unsigned*)d_ws;                             // 8 MB tiled A
  unsigned* bp = ap + (size_t)S_DIM * K_DIM / 4;              // 4 MB tiled B

  const int total = (S_DIM * K_DIM + O_DIM * K_DIM) / 4;      // 3M threads
  pack_kernel<<<(total + 255) / 256, 256, 0, stream>>>(
      x, w, sy, ap, bp, out + (size_t)S_DIM * O_DIM);

  dim3 grid(S_DIM / BM, O_DIM / BN);  // (32, 32)
  gemm_i8_kernel<<<grid, 512, 0, stream>>>(
      (const signed char*)ap, (const signed char*)bp, sx, sw, sy, out);
}

// Round 9
// 198.382 us; speedup vs baseline: 1.0671x; 1.0671x over previous
//
#include <hip/hip_runtime.h>

// Problem: S=8192, K=1024, O=4096
// out_q[s,o] = clip(round(int8dot(x[s,:], w[o,:]) * sx*sw/sy[s]), -128, 127)
// d_out = [ out_q as float (S*O) | scale_y (S) ]
//
// R14 = unbundle R13's two changes: KEEP pack v2 (coalesced 4-lane, output
// image byte-identical to verified), REVERT nontemporal C-stores (4B nt
// stores defeat L2 write-combining -> sub-line HBM write amplification on
// 134 MB; the likely cause of R13's -12 us). Gemm is byte-for-byte R8
// (best, 199.6 us: 256x128, ring-3, vmcnt(3), 16 waves/CU, plain stores).
// History: R7 -20 (occupancy); R8 best; R9 -12.7 / R11 -9.4 (8-phase family);
// R10 0 (XCD swz); R12 -6.3 (32x32 shape); R13 -12 (nt-store suspected).

#define S_DIM 8192
#define K_DIM 1024
#define O_DIM 4096
#define BM 256
#define BN 128
#define BK 64
#define NITER (K_DIM / BK)
#define TILE_BYTES (128 * BK)   // 8192 B band-tile (pack layout unit)
#define A_SLOT (2 * TILE_BYTES) // 16 KB: two band-tiles stacked
#define B_SLOT TILE_BYTES       // 8 KB

using i32x4 = __attribute__((ext_vector_type(4))) int;

__device__ __forceinline__ void load_lds16(const void* g, void* l) {
  __builtin_amdgcn_global_load_lds(
      (const __attribute__((address_space(1))) void*)g,
      (__attribute__((address_space(3))) void*)l, 16, 0, 0);
}

// ---------------- pack v2: int32 -> int8, coalesced 4-lane scheme ------------
// Output image identical to the verified R5/R8 pack:
//   tile t = band*16 + ktile; within tile, byte r*64 + cs*16 holds chunk
//   (cs ^ (r&3)) of row band*128+r.
// Thread q -> chunk j = q>>2, dword sub = q&3. Load: one int4 (16 B) at
// int4-index row*256 + kt*16 + c*4 + sub  (a wave covers 4 rows x 256 B =
// 16 full 64B lines per load instruction -> minimum request count).
// Store: dword at t*2048 + idx*4 + sub  (wave writes 1 KB contiguous).
__global__ void pack_kernel(const int* __restrict__ xi, const int* __restrict__ wi,
                            const float* __restrict__ sy,
                            unsigned* __restrict__ ap, unsigned* __restrict__ bp,
                            float* __restrict__ out_sy) {
  const int tid = blockIdx.x * blockDim.x + threadIdx.x;
  const int nA4 = S_DIM * K_DIM / 4;  // 2M output dwords for A
  const int nB4 = O_DIM * K_DIM / 4;  // 1M output dwords for B

  const int* src;
  unsigned* dst;
  int q;
  if (tid < nA4) {
    src = xi; dst = ap; q = tid;
  } else if (tid < nA4 + nB4) {
    src = wi; dst = bp; q = tid - nA4;
  } else {
    return;
  }
  const int j = q >> 2;          // chunk index
  const int sub = q & 3;         // dword within chunk
  const int t = j >> 9;          // tile index (512 chunks/tile)
  const int idx = j & 511;
  const int r = idx >> 2;        // row within tile 0..127
  const int cs = idx & 3;        // chunk slot
  const int c = cs ^ (r & 3);    // global chunk (swizzle)
  const int band = t >> 4;       // 16 ktiles per band
  const int kt = t & 15;
  const int row = band * 128 + r;
  const int4 v = *((const int4*)src + row * 256 + kt * 16 + c * 4 + sub);
  const unsigned o = (v.x & 0xff) | ((v.y & 0xff) << 8) | ((v.z & 0xff) << 16) |
                     (((unsigned)v.w & 0xff) << 24);
  dst[(size_t)t * 2048 + idx * 4 + sub] = o;
  if (tid < S_DIM) out_sy[tid] = sy[tid];
}

// ---------------- int8 MFMA GEMM, 256x128 tile, ring-3, 16 waves/CU ----------
// (exact R8 structure, plain C-stores)
// 512 threads = 8 waves in 4x2; wave owns 64x64 = 4x4 grid of 16x16x64 tiles.
// 3-slot LDS ring (72 KB, 2 blk/CU), 2-deep prefetch, counted waits:
//   s_waitcnt vmcnt(3) lgkmcnt(0) ; s_barrier ; issue stage(t+2) ; compute(t)
__global__ __launch_bounds__(512, 4) void gemm_i8_kernel(
    const signed char* __restrict__ Ap,  // tiled-packed x
    const signed char* __restrict__ Bp,  // tiled-packed w
    const float* __restrict__ sx, const float* __restrict__ sw,
    const float* __restrict__ sy, float* __restrict__ out) {
  __shared__ __align__(16) signed char As[3][A_SLOT];  // 48 KB
  __shared__ __align__(16) signed char Bs[3][B_SLOT];  // 24 KB

  const int tid = threadIdx.x;
  const int wave = tid >> 6;
  const int lane = tid & 63;
  const int wm = wave >> 1;  // 0..3: wave row in block
  const int wn = wave & 1;   // 0..1: wave col in block
  const int rowBase = blockIdx.x * BM;   // x-fast over S keeps B L2-resident
  const int colBase = blockIdx.y * BN;

  const int soff = wave * 1024 + lane * 16;  // 8 waves cover 8 KB per call
  const signed char* gA0 = Ap + (size_t)(2 * blockIdx.x) * NITER * TILE_BYTES + soff;
  const signed char* gA1 = Ap + (size_t)(2 * blockIdx.x + 1) * NITER * TILE_BYTES + soff;
  const signed char* gB  = Bp + (size_t)blockIdx.y * NITER * TILE_BYTES + soff;
  signed char* ldsA = (signed char*)As + soff;  // + slot*A_SLOT (+TILE for half1)
  signed char* ldsB = (signed char*)Bs + soff;  // + slot*B_SLOT

  i32x4 acc[4][4] = {};

  const int fr = lane & 15;                            // fragment row
  const int fq = (((lane >> 4) ^ (fr & 3)) & 3) * 16;  // swizzled chunk slot

  // Prologue: stage K-tiles 0 and 1 into ring slots 0 and 1 (ordered groups).
  load_lds16(gA0, ldsA);
  load_lds16(gA1, ldsA + TILE_BYTES);
  load_lds16(gB, ldsB);
  asm volatile("" ::: "memory");
  {
    const size_t goff = TILE_BYTES;
    load_lds16(gA0 + goff, ldsA + A_SLOT);
    load_lds16(gA1 + goff, ldsA + A_SLOT + TILE_BYTES);
    load_lds16(gB + goff, ldsB + B_SLOT);
  }

#pragma unroll
  for (int it = 0; it < NITER; ++it) {
    // Drain own stage(it) (oldest 3); keep stage(it+1)'s 3 in flight.
    // lgkmcnt(0): no live ds_read of slot(it-1) before its overwrite below.
    if (it + 1 < NITER) {
      asm volatile("s_waitcnt vmcnt(3) lgkmcnt(0)" ::: "memory");
    } else {
      asm volatile("s_waitcnt vmcnt(0) lgkmcnt(0)" ::: "memory");
    }
    __builtin_amdgcn_s_barrier();
    asm volatile("" ::: "memory");  // no memory op crosses the barrier

    if (it + 2 < NITER) {  // 2-deep prefetch into ring slot (it+2)%3
      const int slot = (it + 2) % 3;
      const size_t goff = (size_t)(it + 2) * TILE_BYTES;
      load_lds16(gA0 + goff, ldsA + slot * A_SLOT);
      load_lds16(gA1 + goff, ldsA + slot * A_SLOT + TILE_BYTES);
      load_lds16(gB + goff, ldsB + slot * B_SLOT);
    }

    const signed char* curA = As[it % 3];
    const signed char* curB = Bs[it % 3];
    i32x4 bf[4];
#pragma unroll
    for (int ni = 0; ni < 4; ++ni)
      bf[ni] = *(const i32x4*)(curB + (wn * 64 + ni * 16 + fr) * BK + fq);

#pragma unroll
    for (int mi = 0; mi < 4; ++mi) {
      i32x4 af = *(const i32x4*)(curA + (wm * 64 + mi * 16 + fr) * BK + fq);
#pragma unroll
      for (int ni = 0; ni < 4; ++ni)
        acc[mi][ni] =
            __builtin_amdgcn_mfma_i32_16x16x64_i8(af, bf[ni], acc[mi][ni], 0, 0, 0);
    }
  }

  // Epilogue. C/D layout: col = lane&15, row = (lane>>4)*4 + reg.
  const float sxw = sx[0] * sw[0];
  const int quad = lane >> 4;
#pragma unroll
  for (int mi = 0; mi < 4; ++mi) {
#pragma unroll
    for (int r = 0; r < 4; ++r) {
      const int s = rowBase + wm * 64 + mi * 16 + quad * 4 + r;
      const float rs = sxw / sy[s];
      float* orow = out + (size_t)s * O_DIM + colBase + wn * 64 + fr;
#pragma unroll
      for (int ni = 0; ni < 4; ++ni) {
        float f = rintf((float)acc[mi][ni][r] * rs);
        f = fminf(127.0f, fmaxf(-128.0f, f));
        orow[ni * 16] = f;
      }
    }
  }
}

extern "C" void kernel_launch(void* const* d_in, const int* in_sizes, int n_in,
                              void* d_out, int out_size, void* d_ws, size_t ws_size,
                              hipStream_t stream) {
  const int* x = (const int*)d_in[0];        // [S,K] int8 values as int32
  const int* w = (const int*)d_in[1];        // [O,K] int8 values as int32
  const float* sx = (const float*)d_in[2];
  const float* sw = (const float*)d_in[3];
  const float* sy = (const float*)d_in[4];   // [S]
  float* out = (float*)d_out;

  unsigned* ap = (unsigned*)d_ws;                             // 8 MB tiled A
  unsigned* bp = ap + (size_t)S_DIM * K_DIM / 4;              // 4 MB tiled B

  const int total = (S_DIM * K_DIM + O_DIM * K_DIM) / 4;      // 3M threads
  pack_kernel<<<(total + 255) / 256, 256, 0, stream>>>(
      x, w, sy, ap, bp, out + (size_t)S_DIM * O_DIM);

  dim3 grid(S_DIM / BM, O_DIM / BN);  // (32, 32)
  gemm_i8_kernel<<<grid, 512, 0, stream>>>(
      (const signed char*)ap, (const signed char*)bp, sx, sw, sy, out);
}